// Round 9
// baseline (355.270 us; speedup 1.0000x reference)
//
#include <hip/hip_runtime.h>
#include <hip/hip_bf16.h>

#define SEQ    576
#define DIM    640
#define HEADS  8
#define HD     80          // DIM / HEADS
#define NF     4
#define NB     12          // 3 * NF
#define M_TOT  (NB * SEQ)  // 6912
#define SCALE  0.11180339887498949f   // 1/sqrt(80)
#define LOG2E  1.4426950408889634f

typedef __attribute__((ext_vector_type(8))) short          bf16x8;
typedef __attribute__((ext_vector_type(4))) float          f32x4;
typedef __attribute__((ext_vector_type(8))) unsigned short u16x8;
typedef __attribute__((ext_vector_type(4))) unsigned short u16x4;

__device__ __forceinline__ unsigned short f2bf(float x) {
    unsigned u = __float_as_uint(x);
    u += 0x7fffu + ((u >> 16) & 1u);
    return (unsigned short)(u >> 16);
}
__device__ __forceinline__ float bf2f(unsigned short h) {
    return __uint_as_float((unsigned)h << 16);
}
__device__ __forceinline__ f32x4 mfma16(bf16x8 a, bf16x8 b, f32x4 c) {
    return __builtin_amdgcn_mfma_f32_16x16x32_bf16(a, b, c, 0, 0, 0);
}
__device__ __forceinline__ float fexp2(float x) {
    return __builtin_amdgcn_exp2f(x);
}
// async global->LDS DMA, 16B/lane, dest = lds base + lane*16
__device__ __forceinline__ void dma16(const void* g, void* s) {
    __builtin_amdgcn_global_load_lds(
        (const __attribute__((address_space(1))) void*)g,
        (__attribute__((address_space(3))) void*)s, 16, 0, 0);
}

// ---------------------------------------------------------------------------
// Convert fp32 -> bf16 (single, round-to-nearest). z: 0=X, 1=Wq(*SCALE*LOG2E),
// 2=Wk, 3=Wv, 4=Wo. grid=(1080,5), block 256, 16 elems/thread.
// W-splits dropped: X/Q/K/V/Oh are already single-bf16, so W hi/lo added only
// equal-order error for 2x the GEMM work (round 8 post-mortem).
// ---------------------------------------------------------------------------
__global__ __launch_bounds__(256) void split_kernel(
    const float* __restrict__ X,  const float* __restrict__ Wq,
    const float* __restrict__ Wk, const float* __restrict__ Wv,
    const float* __restrict__ Wo,
    unsigned short* __restrict__ Xh,  unsigned short* __restrict__ Wqh,
    unsigned short* __restrict__ Wkh, unsigned short* __restrict__ Wvh,
    unsigned short* __restrict__ Woh)
{
    const int z = blockIdx.y;
    const float* src; unsigned short* dh; int n; float s = 1.0f;
    switch (z) {
        case 0:  src = X;  dh = Xh;  n = M_TOT * DIM; break;
        case 1:  src = Wq; dh = Wqh; n = DIM * DIM; s = SCALE * LOG2E; break;
        case 2:  src = Wk; dh = Wkh; n = DIM * DIM; break;
        case 3:  src = Wv; dh = Wvh; n = DIM * DIM; break;
        default: src = Wo; dh = Woh; n = DIM * DIM; break;
    }
    const int base = blockIdx.x * 4096 + threadIdx.x * 16;
    if (base >= n) return;
#pragma unroll
    for (int half = 0; half < 2; ++half) {
        const int b = base + half * 8;
        float4 a4 = *(const float4*)(src + b);
        float4 b4 = *(const float4*)(src + b + 4);
        float vv[8] = {a4.x, a4.y, a4.z, a4.w, b4.x, b4.y, b4.z, b4.w};
        union { unsigned short u[8]; u16x8 v; } ph;
#pragma unroll
        for (int j = 0; j < 8; ++j) ph.u[j] = f2bf(vv[j] * s);
        *(u16x8*)(dh + b) = ph.v;
    }
}

// ---------------------------------------------------------------------------
// QKV GEMM (single bf16). Tile 256(M) x 64(N), BK=32, block 256.
// Staging via global_load_lds (16B/lane), unpadded [r][32] LDS.
// grid=(27,10,3); z epilogue: 0 -> Qh bf16, 1 -> Kb bf16, 2 -> Vt transpose.
// ---------------------------------------------------------------------------
__global__ __launch_bounds__(256) void qkv_mfma_kernel(
    const unsigned short* __restrict__ Xh,
    const unsigned short* __restrict__ Wqh, const unsigned short* __restrict__ Wkh,
    const unsigned short* __restrict__ Wvh,
    unsigned short* __restrict__ Qh,
    unsigned short* __restrict__ Kb, unsigned short* __restrict__ VtG)
{
    __shared__ unsigned short smem[10240];      // 20 KB
    unsigned short* As = smem;                  // 256*32
    unsigned short* Bs = smem + 8192;           // 64*32

    const int z = blockIdx.z;
    const unsigned short* WH = (z == 0) ? Wqh : ((z == 1) ? Wkh : Wvh);
    const int m0 = blockIdx.x * 256;
    const int n0 = blockIdx.y * 64;

    const int t    = threadIdx.x;
    const int w    = t >> 6;
    const int lane = t & 63;
    const int quad = lane >> 4;
    const int ln   = lane & 15;

    f32x4 acc[4][4];
#pragma unroll
    for (int mi = 0; mi < 4; ++mi)
#pragma unroll
        for (int nt = 0; nt < 4; ++nt)
#pragma unroll
            for (int e = 0; e < 4; ++e) acc[mi][nt][e] = 0.f;

    const int lr = lane >> 2;          // 0..15 (row within 16-row DMA chunk)
    const int lc = (lane & 3) * 8;     // 0,8,16,24 (shorts)

    for (int k0 = 0; k0 < DIM; k0 += 32) {
        __syncthreads();
        {   // A: wave w stages its own 64 rows (4 x 1KB DMA)
            const unsigned short* gp = Xh + (size_t)(m0 + w * 64 + lr) * DIM + k0 + lc;
#pragma unroll
            for (int i = 0; i < 4; ++i)
                dma16(gp + (size_t)i * 16 * DIM, &As[(w * 64 + i * 16) * 32]);
            // B: wave w stages rows [w*16, w*16+16)
            const size_t gb = (size_t)(n0 + w * 16 + lr) * DIM + k0 + lc;
            dma16(WH + gb, &Bs[w * 16 * 32]);
        }
        __syncthreads();

        bf16x8 af[4];
#pragma unroll
        for (int mi = 0; mi < 4; ++mi)
            af[mi] = *(const bf16x8*)&As[(w * 64 + mi * 16 + ln) * 32 + quad * 8];
#pragma unroll
        for (int nt = 0; nt < 4; ++nt) {
            bf16x8 bh = *(const bf16x8*)&Bs[(nt * 16 + ln) * 32 + quad * 8];
#pragma unroll
            for (int mi = 0; mi < 4; ++mi)
                acc[mi][nt] = mfma16(af[mi], bh, acc[mi][nt]);
        }
    }

    if (z == 0) {
#pragma unroll
        for (int mi = 0; mi < 4; ++mi)
#pragma unroll
            for (int r = 0; r < 4; ++r) {
                const size_t row = m0 + w * 64 + mi * 16 + quad * 4 + r;
#pragma unroll
                for (int nt = 0; nt < 4; ++nt)
                    Qh[row * DIM + n0 + nt * 16 + ln] = f2bf(acc[mi][nt][r]);
            }
    } else if (z == 1) {
#pragma unroll
        for (int mi = 0; mi < 4; ++mi)
#pragma unroll
            for (int r = 0; r < 4; ++r) {
                const size_t row = m0 + w * 64 + mi * 16 + quad * 4 + r;
#pragma unroll
                for (int nt = 0; nt < 4; ++nt)
                    Kb[row * DIM + n0 + nt * 16 + ln] = f2bf(acc[mi][nt][r]);
            }
    } else {
        // transpose 256x64 -> Vt[64 n][256 m] in two 128-col halves via LDS
        unsigned short* Vts = smem;   // 64 x 136 = 8704 shorts
#pragma unroll 1
        for (int half = 0; half < 2; ++half) {
            __syncthreads();
            if ((w >> 1) == half) {
                const int wl = w & 1;
#pragma unroll
                for (int mi = 0; mi < 4; ++mi)
#pragma unroll
                    for (int nt = 0; nt < 4; ++nt)
#pragma unroll
                        for (int r = 0; r < 4; ++r)
                            Vts[(nt * 16 + ln) * 136 + wl * 64 + mi * 16 + quad * 4 + r] =
                                f2bf(acc[mi][nt][r]);
            }
            __syncthreads();
            const int nn = t & 63;
            const int c0 = (t >> 6) * 32;
#pragma unroll
            for (int i = 0; i < 4; ++i)
                *(u16x8*)(VtG + (size_t)(n0 + nn) * M_TOT + m0 + half * 128 + c0 + i * 8) =
                    *(const u16x8*)&Vts[nn * 136 + c0 + i * 8];
        }
    }
}

// ---------------------------------------------------------------------------
// Flash attention v6. grid=(6,8,20), block 128 (2 waves x 48 q-rows = 96-row
// Q-tile). Single-bf16 Q (scale*log2e folded into Wq).
// K staged via DMA into stride-96 KhS (768 units = 6 rounds x 128 lanes);
// pad cols carry real adjacent K data (finite) hitting zeroed Q-frag slots.
// NOTE: never leave MFMA-read LDS uninitialized — 0*NaN = NaN (round-7 bug).
// V staged into exact-fit stride-64 VtS with (c8+3d)&7 col-group swizzle.
// z<16: cross chunk -> partials (Pn,ml); z>=16: self frame -> Oh.
// ---------------------------------------------------------------------------
__global__ __launch_bounds__(128, 4) void attn_mfma_kernel(
    const unsigned short* __restrict__ Qh,
    const unsigned short* __restrict__ Kb, const unsigned short* __restrict__ Vt,
    unsigned short* __restrict__ Oh,
    unsigned short* __restrict__ Pn, float2* __restrict__ ml)
{
    const int qt = blockIdx.x;   // 0..5 (96-row tiles)
    const int h  = blockIdx.y;   // 0..7
    const int z  = blockIdx.z;   // 0..19

    int f, kbase, nkt, idx = -1;
    if (z < 16) {
        idx = z;
        const int fi = z >> 1;
        f = 4 + fi;
        kbase = ((fi < 4 ? 4 : 8) + (z & 1) * 2) * SEQ;
        nkt = 18;
    } else {
        f = z - 16;
        kbase = f * SEQ;
        nkt = 9;
    }

    const int t    = threadIdx.x;
    const int w    = t >> 6;
    const int lane = t & 63;
    const int quad = lane >> 4;
    const int ln   = lane & 15;

    __shared__ unsigned short KhS[64 * 96];    // DMA-staged, fully written/iter
    __shared__ unsigned short VtS[80 * 64];    // exact-fit, swizzled cols
    __shared__ unsigned short Pb[2 * 48 * 72]; // per-wave P (48 rows), swizzled

    // ---- Q fragments: wave w owns rows w*48 + mi*16 + ln (mi=0..2) ----
    bf16x8 qf[3][3];
#pragma unroll
    for (int mi = 0; mi < 3; ++mi) {
        const int qrow = f * SEQ + qt * 96 + w * 48 + mi * 16 + ln;
        const unsigned short* qp = Qh + (size_t)qrow * DIM + h * HD;
#pragma unroll
        for (int kc = 0; kc < 3; ++kc) {
            const int dbase = kc * 32 + quad * 8;
            if (dbase < HD) {
                qf[mi][kc] = *(const bf16x8*)(qp + dbase);
            } else {
                union { unsigned short u[8]; bf16x8 v; } zz;
#pragma unroll
                for (int j = 0; j < 8; ++j) zz.u[j] = 0;
                qf[mi][kc] = zz.v;
            }
        }
    }

    float m_[3][4], l_[3][4];
#pragma unroll
    for (int mi = 0; mi < 3; ++mi)
#pragma unroll
        for (int r = 0; r < 4; ++r) { m_[mi][r] = -INFINITY; l_[mi][r] = 0.f; }

    f32x4 oacc[3][5];
#pragma unroll
    for (int mi = 0; mi < 3; ++mi)
#pragma unroll
        for (int nt = 0; nt < 5; ++nt)
#pragma unroll
            for (int e = 0; e < 4; ++e) oacc[mi][nt][e] = 0.f;

    unsigned short* PbW = &Pb[w * 48 * 72];

    for (int kt = 0; kt < nkt; ++kt) {
        __syncthreads();
        {   // ---- K stage via DMA: 64 rows x 96 shorts = 768 units, 6 rounds ----
            const unsigned short* kg = Kb + (size_t)(kbase + kt * 64) * DIM + h * HD;
#pragma unroll
            for (int rnd = 0; rnd < 6; ++rnd) {
                const int unit = rnd * 128 + t;
                const int kr = unit / 12, kc = unit % 12;
                dma16(kg + (size_t)kr * DIM + kc * 8,
                      &KhS[(rnd * 128 + w * 64) * 8]);
            }
        }
        {   // ---- V stage: 80 d-rows x 64 keys, swizzled col-groups ----
#pragma unroll
            for (int u = t; u < 640; u += 128) {
                const int d = u >> 3, c8 = u & 7;
                const int c8s = (c8 + 3 * d) & 7;
                *(u16x8*)&VtS[d * 64 + c8s * 8] =
                    *(const u16x8*)(Vt + (size_t)(h * HD + d) * M_TOT +
                                    kbase + kt * 64 + c8 * 8);
            }
        }
        __syncthreads();

        // ---- S = Q.K^T: 48 rows x 64 keys per wave ----
        f32x4 sacc[3][4];
#pragma unroll
        for (int mi = 0; mi < 3; ++mi)
#pragma unroll
            for (int nt = 0; nt < 4; ++nt)
#pragma unroll
                for (int e = 0; e < 4; ++e) sacc[mi][nt][e] = 0.f;
#pragma unroll
        for (int nt = 0; nt < 4; ++nt)
#pragma unroll
            for (int kc = 0; kc < 3; ++kc) {
                bf16x8 kf = *(const bf16x8*)&KhS[(nt * 16 + ln) * 96 + kc * 32 + quad * 8];
#pragma unroll
                for (int mi = 0; mi < 3; ++mi)
                    sacc[mi][nt] = mfma16(qf[mi][kc], kf, sacc[mi][nt]);
            }

        // ---- in-register online softmax (reduce over ln lanes) ----
        float alpha[3][4];
#pragma unroll
        for (int mi = 0; mi < 3; ++mi)
#pragma unroll
            for (int r = 0; r < 4; ++r) {
                float mx = fmaxf(fmaxf(sacc[mi][0][r], sacc[mi][1][r]),
                                 fmaxf(sacc[mi][2][r], sacc[mi][3][r]));
                mx = fmaxf(mx, __shfl_xor(mx, 1));
                mx = fmaxf(mx, __shfl_xor(mx, 2));
                mx = fmaxf(mx, __shfl_xor(mx, 4));
                mx = fmaxf(mx, __shfl_xor(mx, 8));
                float mnew = fmaxf(m_[mi][r], mx);
                alpha[mi][r] = fexp2(m_[mi][r] - mnew);
                m_[mi][r] = mnew;
            }
        float rs[3][4] = {};
#pragma unroll
        for (int nt = 0; nt < 4; ++nt) {
            const int colx = (nt * 16 + ln) ^ ((quad & 2) * 8);  // ^16 when quad>=2
#pragma unroll
            for (int mi = 0; mi < 3; ++mi)
#pragma unroll
                for (int r = 0; r < 4; ++r) {
                    float p = fexp2(sacc[mi][nt][r] - m_[mi][r]);
                    rs[mi][r] += p;
                    PbW[(mi * 16 + quad * 4 + r) * 72 + colx] =
                        (unsigned short)(__float_as_uint(p) >> 16);   // trunc bf16
                }
        }
#pragma unroll
        for (int mi = 0; mi < 3; ++mi)
#pragma unroll
            for (int r = 0; r < 4; ++r) {
                float s = rs[mi][r];
                s += __shfl_xor(s, 1);
                s += __shfl_xor(s, 2);
                s += __shfl_xor(s, 4);
                s += __shfl_xor(s, 8);
                l_[mi][r] = l_[mi][r] * alpha[mi][r] + s;
#pragma unroll
                for (int nt = 0; nt < 5; ++nt) oacc[mi][nt][r] *= alpha[mi][r];
            }

        __threadfence_block();   // wave-private P region: lgkm drain only

        // ---- O += P.V ----
#pragma unroll
        for (int kc = 0; kc < 2; ++kc) {
            const int cbase = (kc * 32 + quad * 8) ^ (((ln >> 2) & 2) * 8);
            bf16x8 pf[3];
#pragma unroll
            for (int mi = 0; mi < 3; ++mi)
                pf[mi] = *(const bf16x8*)&PbW[(mi * 16 + ln) * 72 + cbase];
#pragma unroll
            for (int nt = 0; nt < 5; ++nt) {
                const int vrow = nt * 16 + ln;
                const int c8r  = ((kc * 4 + quad) + 3 * vrow) & 7;
                bf16x8 vf = *(const bf16x8*)&VtS[vrow * 64 + c8r * 8];
#pragma unroll
                for (int mi = 0; mi < 3; ++mi)
                    oacc[mi][nt] = mfma16(pf[mi], vf, oacc[mi][nt]);
            }
        }
    }

    // ---- epilogue (576 = 6*96: no masking) ----
#pragma unroll
    for (int mi = 0; mi < 3; ++mi)
#pragma unroll
        for (int r = 0; r < 4; ++r) {
            const int rr = qt * 96 + w * 48 + mi * 16 + quad * 4 + r;  // frame-local
            const float inv = 1.f / l_[mi][r];
            if (idx < 0) {
                const size_t orow = (size_t)f * SEQ + rr;
#pragma unroll
                for (int nt = 0; nt < 5; ++nt)
                    Oh[orow * DIM + h * HD + nt * 16 + ln] = f2bf(oacc[mi][nt][r] * inv);
            } else {
#pragma unroll
                for (int nt = 0; nt < 5; ++nt)
                    Pn[((size_t)idx * SEQ + rr) * DIM + h * HD + nt * 16 + ln] =
                        f2bf(oacc[mi][nt][r] * inv);
                if (ln == 0)
                    ml[((size_t)idx * 8 + h) * SEQ + rr] = make_float2(m_[mi][r], l_[mi][r]);
            }
        }
}

// ---------------------------------------------------------------------------
// Merge the two partials of each cross frame. grid=(576,8), block 320.
// ---------------------------------------------------------------------------
__global__ __launch_bounds__(320) void merge_kernel(
    const unsigned short* __restrict__ Pn, const float2* __restrict__ ml,
    unsigned short* __restrict__ Oh)
{
    const int row = blockIdx.x;   // 0..575
    const int fi  = blockIdx.y;   // 0..7
    const int t   = threadIdx.x;  // 0..319
    const int i0  = fi * 2, i1 = i0 + 1;
#pragma unroll
    for (int rep = 0; rep < 2; ++rep) {
        const int col = t + rep * 320;
        const int h = col / 80;
        const float2 a = ml[((size_t)i0 * 8 + h) * SEQ + row];
        const float2 b = ml[((size_t)i1 * 8 + h) * SEQ + row];
        const float M  = fmaxf(a.x, b.x);
        const float w0 = fexp2(a.x - M) * a.y;
        const float w1 = fexp2(b.x - M) * b.y;
        const float inv = 1.f / (w0 + w1);
        const float p0 = bf2f(Pn[((size_t)i0 * SEQ + row) * DIM + col]);
        const float p1 = bf2f(Pn[((size_t)i1 * SEQ + row) * DIM + col]);
        Oh[((size_t)(4 + fi) * SEQ + row) * DIM + col] = f2bf((w0 * p0 + w1 * p1) * inv);
    }
}

// ---------------------------------------------------------------------------
// Output projection: out = Oh * Wo^T + bo (single bf16), fp32 out.
// Tile 256x64, BK=32, global_load_lds staging. grid=(27,10).
// ---------------------------------------------------------------------------
__global__ __launch_bounds__(256) void oproj_mfma_kernel(
    const unsigned short* __restrict__ Oh,
    const unsigned short* __restrict__ Woh,
    const float* __restrict__ bo, float* __restrict__ out)
{
    __shared__ unsigned short smem[10240];
    unsigned short* As = smem;
    unsigned short* Bs = smem + 8192;

    const int m0 = blockIdx.x * 256;
    const int n0 = blockIdx.y * 64;

    const int t    = threadIdx.x;
    const int w    = t >> 6;
    const int lane = t & 63;
    const int quad = lane >> 4;
    const int ln   = lane & 15;

    f32x4 acc[4][4];
#pragma unroll
    for (int mi = 0; mi < 4; ++mi)
#pragma unroll
        for (int nt = 0; nt < 4; ++nt)
#pragma unroll
            for (int e = 0; e < 4; ++e) acc[mi][nt][e] = 0.f;

    const int lr = lane >> 2;
    const int lc = (lane & 3) * 8;

    for (int k0 = 0; k0 < DIM; k0 += 32) {
        __syncthreads();
        {
            const unsigned short* gp = Oh + (size_t)(m0 + w * 64 + lr) * DIM + k0 + lc;
#pragma unroll
            for (int i = 0; i < 4; ++i)
                dma16(gp + (size_t)i * 16 * DIM, &As[(w * 64 + i * 16) * 32]);
            const size_t gb = (size_t)(n0 + w * 16 + lr) * DIM + k0 + lc;
            dma16(Woh + gb, &Bs[w * 16 * 32]);
        }
        __syncthreads();

        bf16x8 af[4];
#pragma unroll
        for (int mi = 0; mi < 4; ++mi)
            af[mi] = *(const bf16x8*)&As[(w * 64 + mi * 16 + ln) * 32 + quad * 8];
#pragma unroll
        for (int nt = 0; nt < 4; ++nt) {
            bf16x8 bh = *(const bf16x8*)&Bs[(nt * 16 + ln) * 32 + quad * 8];
#pragma unroll
            for (int mi = 0; mi < 4; ++mi)
                acc[mi][nt] = mfma16(af[mi], bh, acc[mi][nt]);
        }
    }

#pragma unroll
    for (int mi = 0; mi < 4; ++mi)
#pragma unroll
        for (int r = 0; r < 4; ++r) {
            const size_t row = m0 + w * 64 + mi * 16 + quad * 4 + r;
#pragma unroll
            for (int nt = 0; nt < 4; ++nt) {
                const int col = n0 + nt * 16 + ln;
                out[row * DIM + col] = acc[mi][nt][r] + bo[col];
            }
        }
}

// ---------------------------------------------------------------------------
extern "C" void kernel_launch(void* const* d_in, const int* in_sizes, int n_in,
                              void* d_out, int out_size, void* d_ws, size_t ws_size,
                              hipStream_t stream)
{
    const float* x  = (const float*)d_in[0];
    const float* Wq = (const float*)d_in[1];
    const float* Wk = (const float*)d_in[2];
    const float* Wv = (const float*)d_in[3];
    const float* Wo = (const float*)d_in[4];
    const float* bo = (const float*)d_in[5];
    float* out = (float*)d_out;

    const size_t NX = (size_t)M_TOT * DIM;   // 4,423,680
    const size_t NW = (size_t)DIM * DIM;     // 409,600
    unsigned short* p = (unsigned short*)d_ws;
    unsigned short* Wqh = p;  p += NW;
    unsigned short* Wkh = p;  p += NW;
    unsigned short* Wvh = p;  p += NW;
    unsigned short* Woh = p;  p += NW;
    unsigned short* Xh  = p;  p += NX;
    unsigned short* Qhb = p;  p += NX;
    unsigned short* Kbb = p;  p += NX;
    unsigned short* Vtb = p;  p += NX;
    unsigned short* Ohb = Xh;                 // Xh dead after QKV GEMM

    // flash-decoding partials live in d_out (dead until oproj rewrites it)
    unsigned short* Pn = (unsigned short*)d_out;            // 16*576*640 bf16
    float2* ml = (float2*)((char*)d_out + (size_t)16 * SEQ * DIM * 2);

    dim3 g0((unsigned)((NX + 4095) / 4096), 5);
    split_kernel<<<g0, 256, 0, stream>>>(x, Wq, Wk, Wv, Wo,
        Xh, Wqh, Wkh, Wvh, Woh);

    dim3 g1(M_TOT / 256, DIM / 64, 3);
    qkv_mfma_kernel<<<g1, 256, 0, stream>>>(Xh, Wqh, Wkh, Wvh, Qhb, Kbb, Vtb);

    dim3 g2(6, HEADS, 20);
    attn_mfma_kernel<<<g2, 128, 0, stream>>>(Qhb, Kbb, Vtb, Ohb, Pn, ml);

    dim3 g3(SEQ, 8);
    merge_kernel<<<g3, 320, 0, stream>>>(Pn, ml, Ohb);

    dim3 g4(M_TOT / 256, DIM / 64);
    oproj_mfma_kernel<<<g4, 256, 0, stream>>>(Ohb, Woh, bo, out);
}

// Round 10
// 272.905 us; speedup vs baseline: 1.3018x; 1.3018x over previous
//
#include <hip/hip_runtime.h>
#include <hip/hip_bf16.h>

#define SEQ    576
#define DIM    640
#define HEADS  8
#define HD     80          // DIM / HEADS
#define NF     4
#define NB     12          // 3 * NF
#define M_TOT  (NB * SEQ)  // 6912
#define SCALE  0.11180339887498949f   // 1/sqrt(80)
#define LOG2E  1.4426950408889634f

typedef __attribute__((ext_vector_type(8))) short          bf16x8;
typedef __attribute__((ext_vector_type(4))) float          f32x4;
typedef __attribute__((ext_vector_type(8))) unsigned short u16x8;
typedef __attribute__((ext_vector_type(4))) unsigned short u16x4;

__device__ __forceinline__ unsigned short f2bf(float x) {
    unsigned u = __float_as_uint(x);
    u += 0x7fffu + ((u >> 16) & 1u);
    return (unsigned short)(u >> 16);
}
__device__ __forceinline__ float bf2f(unsigned short h) {
    return __uint_as_float((unsigned)h << 16);
}
__device__ __forceinline__ f32x4 mfma16(bf16x8 a, bf16x8 b, f32x4 c) {
    return __builtin_amdgcn_mfma_f32_16x16x32_bf16(a, b, c, 0, 0, 0);
}
__device__ __forceinline__ float fexp2(float x) {
    return __builtin_amdgcn_exp2f(x);
}
// async global->LDS DMA, 16B/lane, dest = lds base + lane*16
__device__ __forceinline__ void dma16(const void* g, void* s) {
    __builtin_amdgcn_global_load_lds(
        (const __attribute__((address_space(1))) void*)g,
        (__attribute__((address_space(3))) void*)s, 16, 0, 0);
}

// ---------------------------------------------------------------------------
// Convert fp32 -> bf16 (single, round-to-nearest). z: 0=X, 1=Wq(*SCALE*LOG2E),
// 2=Wk, 3=Wv, 4=Wo. grid=(1080,5), block 256, 16 elems/thread.
// ---------------------------------------------------------------------------
__global__ __launch_bounds__(256) void split_kernel(
    const float* __restrict__ X,  const float* __restrict__ Wq,
    const float* __restrict__ Wk, const float* __restrict__ Wv,
    const float* __restrict__ Wo,
    unsigned short* __restrict__ Xh,  unsigned short* __restrict__ Wqh,
    unsigned short* __restrict__ Wkh, unsigned short* __restrict__ Wvh,
    unsigned short* __restrict__ Woh)
{
    const int z = blockIdx.y;
    const float* src; unsigned short* dh; int n; float s = 1.0f;
    switch (z) {
        case 0:  src = X;  dh = Xh;  n = M_TOT * DIM; break;
        case 1:  src = Wq; dh = Wqh; n = DIM * DIM; s = SCALE * LOG2E; break;
        case 2:  src = Wk; dh = Wkh; n = DIM * DIM; break;
        case 3:  src = Wv; dh = Wvh; n = DIM * DIM; break;
        default: src = Wo; dh = Woh; n = DIM * DIM; break;
    }
    const int base = blockIdx.x * 4096 + threadIdx.x * 16;
    if (base >= n) return;
#pragma unroll
    for (int half = 0; half < 2; ++half) {
        const int b = base + half * 8;
        float4 a4 = *(const float4*)(src + b);
        float4 b4 = *(const float4*)(src + b + 4);
        float vv[8] = {a4.x, a4.y, a4.z, a4.w, b4.x, b4.y, b4.z, b4.w};
        union { unsigned short u[8]; u16x8 v; } ph;
#pragma unroll
        for (int j = 0; j < 8; ++j) ph.u[j] = f2bf(vv[j] * s);
        *(u16x8*)(dh + b) = ph.v;
    }
}

// ---------------------------------------------------------------------------
// QKV GEMM (single bf16). Tile 256(M) x 64(N), BK=32, block 256.
// Staging via global_load_lds (16B/lane), unpadded [r][32] LDS.
// grid=(27,10,3); z epilogue: 0 -> Qh bf16, 1 -> Kb bf16, 2 -> Vt transpose.
// ---------------------------------------------------------------------------
__global__ __launch_bounds__(256) void qkv_mfma_kernel(
    const unsigned short* __restrict__ Xh,
    const unsigned short* __restrict__ Wqh, const unsigned short* __restrict__ Wkh,
    const unsigned short* __restrict__ Wvh,
    unsigned short* __restrict__ Qh,
    unsigned short* __restrict__ Kb, unsigned short* __restrict__ VtG)
{
    __shared__ unsigned short smem[10240];      // 20 KB
    unsigned short* As = smem;                  // 256*32
    unsigned short* Bs = smem + 8192;           // 64*32

    const int z = blockIdx.z;
    const unsigned short* WH = (z == 0) ? Wqh : ((z == 1) ? Wkh : Wvh);
    const int m0 = blockIdx.x * 256;
    const int n0 = blockIdx.y * 64;

    const int t    = threadIdx.x;
    const int w    = t >> 6;
    const int lane = t & 63;
    const int quad = lane >> 4;
    const int ln   = lane & 15;

    f32x4 acc[4][4];
#pragma unroll
    for (int mi = 0; mi < 4; ++mi)
#pragma unroll
        for (int nt = 0; nt < 4; ++nt)
#pragma unroll
            for (int e = 0; e < 4; ++e) acc[mi][nt][e] = 0.f;

    const int lr = lane >> 2;          // 0..15 (row within 16-row DMA chunk)
    const int lc = (lane & 3) * 8;     // 0,8,16,24 (shorts)

    for (int k0 = 0; k0 < DIM; k0 += 32) {
        __syncthreads();
        {   // A: wave w stages its own 64 rows (4 x 1KB DMA)
            const unsigned short* gp = Xh + (size_t)(m0 + w * 64 + lr) * DIM + k0 + lc;
#pragma unroll
            for (int i = 0; i < 4; ++i)
                dma16(gp + (size_t)i * 16 * DIM, &As[(w * 64 + i * 16) * 32]);
            // B: wave w stages rows [w*16, w*16+16)
            const size_t gb = (size_t)(n0 + w * 16 + lr) * DIM + k0 + lc;
            dma16(WH + gb, &Bs[w * 16 * 32]);
        }
        __syncthreads();

        bf16x8 af[4];
#pragma unroll
        for (int mi = 0; mi < 4; ++mi)
            af[mi] = *(const bf16x8*)&As[(w * 64 + mi * 16 + ln) * 32 + quad * 8];
#pragma unroll
        for (int nt = 0; nt < 4; ++nt) {
            bf16x8 bh = *(const bf16x8*)&Bs[(nt * 16 + ln) * 32 + quad * 8];
#pragma unroll
            for (int mi = 0; mi < 4; ++mi)
                acc[mi][nt] = mfma16(af[mi], bh, acc[mi][nt]);
        }
    }

    if (z == 0) {
#pragma unroll
        for (int mi = 0; mi < 4; ++mi)
#pragma unroll
            for (int r = 0; r < 4; ++r) {
                const size_t row = m0 + w * 64 + mi * 16 + quad * 4 + r;
#pragma unroll
                for (int nt = 0; nt < 4; ++nt)
                    Qh[row * DIM + n0 + nt * 16 + ln] = f2bf(acc[mi][nt][r]);
            }
    } else if (z == 1) {
#pragma unroll
        for (int mi = 0; mi < 4; ++mi)
#pragma unroll
            for (int r = 0; r < 4; ++r) {
                const size_t row = m0 + w * 64 + mi * 16 + quad * 4 + r;
#pragma unroll
                for (int nt = 0; nt < 4; ++nt)
                    Kb[row * DIM + n0 + nt * 16 + ln] = f2bf(acc[mi][nt][r]);
            }
    } else {
        // transpose 256x64 -> Vt[64 n][256 m] in two 128-col halves via LDS
        unsigned short* Vts = smem;   // 64 x 136 = 8704 shorts
#pragma unroll 1
        for (int half = 0; half < 2; ++half) {
            __syncthreads();
            if ((w >> 1) == half) {
                const int wl = w & 1;
#pragma unroll
                for (int mi = 0; mi < 4; ++mi)
#pragma unroll
                    for (int nt = 0; nt < 4; ++nt)
#pragma unroll
                        for (int r = 0; r < 4; ++r)
                            Vts[(nt * 16 + ln) * 136 + wl * 64 + mi * 16 + quad * 4 + r] =
                                f2bf(acc[mi][nt][r]);
            }
            __syncthreads();
            const int nn = t & 63;
            const int c0 = (t >> 6) * 32;
#pragma unroll
            for (int i = 0; i < 4; ++i)
                *(u16x8*)(VtG + (size_t)(n0 + nn) * M_TOT + m0 + half * 128 + c0 + i * 8) =
                    *(const u16x8*)&Vts[nn * 136 + c0 + i * 8];
        }
    }
}

// ---------------------------------------------------------------------------
// Flash attention (round-8 config: measured 102 us). grid=(3,8,20), block 256
// (4 waves x 48 q-rows = 192-row Q-tile). Single-bf16 Q (scale*log2e in Wq).
// K staged via DMA into stride-96 KhS (768 units = 3 rounds x 256 lanes);
// pad cols carry real adjacent K data (finite) hitting zeroed Q-frag slots.
// NOTE: never leave MFMA-read LDS uninitialized — 0*NaN = NaN (round-7 bug).
// NOTE: 128-thread blocks double FETCH + VGPR (round-9 regression) — keep 256.
// V staged into exact-fit stride-64 VtS with (c8+3d)&7 col-group swizzle.
// z<16: cross chunk -> partials (Pn,ml); z>=16: self frame -> Oh.
// ---------------------------------------------------------------------------
__global__ __launch_bounds__(256, 2) void attn_mfma_kernel(
    const unsigned short* __restrict__ Qh,
    const unsigned short* __restrict__ Kb, const unsigned short* __restrict__ Vt,
    unsigned short* __restrict__ Oh,
    unsigned short* __restrict__ Pn, float2* __restrict__ ml)
{
    const int qt = blockIdx.x;   // 0..2
    const int h  = blockIdx.y;   // 0..7
    const int z  = blockIdx.z;   // 0..19

    int f, kbase, nkt, idx = -1;
    if (z < 16) {
        idx = z;
        const int fi = z >> 1;
        f = 4 + fi;
        kbase = ((fi < 4 ? 4 : 8) + (z & 1) * 2) * SEQ;
        nkt = 18;
    } else {
        f = z - 16;
        kbase = f * SEQ;
        nkt = 9;
    }

    const int t    = threadIdx.x;
    const int w    = t >> 6;
    const int lane = t & 63;
    const int quad = lane >> 4;
    const int ln   = lane & 15;

    __shared__ unsigned short KhS[64 * 96];    // DMA-staged, fully written/iter
    __shared__ unsigned short VtS[80 * 64];    // exact-fit, swizzled cols
    __shared__ unsigned short Pb[4 * 48 * 72]; // per-wave P (48 rows), swizzled

    // ---- Q fragments: wave w owns rows w*48 + mi*16 + ln (mi=0..2) ----
    bf16x8 qf[3][3];
#pragma unroll
    for (int mi = 0; mi < 3; ++mi) {
        const int qrow = f * SEQ + qt * 192 + w * 48 + mi * 16 + ln;
        const unsigned short* qp = Qh + (size_t)qrow * DIM + h * HD;
#pragma unroll
        for (int kc = 0; kc < 3; ++kc) {
            const int dbase = kc * 32 + quad * 8;
            if (dbase < HD) {
                qf[mi][kc] = *(const bf16x8*)(qp + dbase);
            } else {
                union { unsigned short u[8]; bf16x8 v; } zz;
#pragma unroll
                for (int j = 0; j < 8; ++j) zz.u[j] = 0;
                qf[mi][kc] = zz.v;
            }
        }
    }

    float m_[3][4], l_[3][4];
#pragma unroll
    for (int mi = 0; mi < 3; ++mi)
#pragma unroll
        for (int r = 0; r < 4; ++r) { m_[mi][r] = -INFINITY; l_[mi][r] = 0.f; }

    f32x4 oacc[3][5];
#pragma unroll
    for (int mi = 0; mi < 3; ++mi)
#pragma unroll
        for (int nt = 0; nt < 5; ++nt)
#pragma unroll
            for (int e = 0; e < 4; ++e) oacc[mi][nt][e] = 0.f;

    unsigned short* PbW = &Pb[w * 48 * 72];

    for (int kt = 0; kt < nkt; ++kt) {
        __syncthreads();
        {   // ---- K stage via DMA: 64 rows x 96 shorts = 768 units, 3 rounds ----
            const unsigned short* kg = Kb + (size_t)(kbase + kt * 64) * DIM + h * HD;
#pragma unroll
            for (int rnd = 0; rnd < 3; ++rnd) {
                const int unit = rnd * 256 + t;
                const int kr = unit / 12, kc = unit % 12;
                dma16(kg + (size_t)kr * DIM + kc * 8,
                      &KhS[(rnd * 256 + w * 64) * 8]);
            }
        }
        {   // ---- V stage: 80 d-rows x 64 keys, swizzled col-groups ----
#pragma unroll
            for (int u = t; u < 640; u += 256) {
                const int d = u >> 3, c8 = u & 7;
                const int c8s = (c8 + 3 * d) & 7;
                *(u16x8*)&VtS[d * 64 + c8s * 8] =
                    *(const u16x8*)(Vt + (size_t)(h * HD + d) * M_TOT +
                                    kbase + kt * 64 + c8 * 8);
            }
        }
        __syncthreads();

        // ---- S = Q.K^T: 48 rows x 64 keys per wave ----
        f32x4 sacc[3][4];
#pragma unroll
        for (int mi = 0; mi < 3; ++mi)
#pragma unroll
            for (int nt = 0; nt < 4; ++nt)
#pragma unroll
                for (int e = 0; e < 4; ++e) sacc[mi][nt][e] = 0.f;
#pragma unroll
        for (int nt = 0; nt < 4; ++nt)
#pragma unroll
            for (int kc = 0; kc < 3; ++kc) {
                bf16x8 kf = *(const bf16x8*)&KhS[(nt * 16 + ln) * 96 + kc * 32 + quad * 8];
#pragma unroll
                for (int mi = 0; mi < 3; ++mi)
                    sacc[mi][nt] = mfma16(qf[mi][kc], kf, sacc[mi][nt]);
            }

        // ---- in-register online softmax (reduce over ln lanes) ----
        float alpha[3][4];
#pragma unroll
        for (int mi = 0; mi < 3; ++mi)
#pragma unroll
            for (int r = 0; r < 4; ++r) {
                float mx = fmaxf(fmaxf(sacc[mi][0][r], sacc[mi][1][r]),
                                 fmaxf(sacc[mi][2][r], sacc[mi][3][r]));
                mx = fmaxf(mx, __shfl_xor(mx, 1));
                mx = fmaxf(mx, __shfl_xor(mx, 2));
                mx = fmaxf(mx, __shfl_xor(mx, 4));
                mx = fmaxf(mx, __shfl_xor(mx, 8));
                float mnew = fmaxf(m_[mi][r], mx);
                alpha[mi][r] = fexp2(m_[mi][r] - mnew);
                m_[mi][r] = mnew;
            }
        float rs[3][4] = {};
#pragma unroll
        for (int nt = 0; nt < 4; ++nt) {
            const int colx = (nt * 16 + ln) ^ ((quad & 2) * 8);  // ^16 when quad>=2
#pragma unroll
            for (int mi = 0; mi < 3; ++mi)
#pragma unroll
                for (int r = 0; r < 4; ++r) {
                    float p = fexp2(sacc[mi][nt][r] - m_[mi][r]);
                    rs[mi][r] += p;
                    PbW[(mi * 16 + quad * 4 + r) * 72 + colx] =
                        (unsigned short)(__float_as_uint(p) >> 16);   // trunc bf16
                }
        }
#pragma unroll
        for (int mi = 0; mi < 3; ++mi)
#pragma unroll
            for (int r = 0; r < 4; ++r) {
                float s = rs[mi][r];
                s += __shfl_xor(s, 1);
                s += __shfl_xor(s, 2);
                s += __shfl_xor(s, 4);
                s += __shfl_xor(s, 8);
                l_[mi][r] = l_[mi][r] * alpha[mi][r] + s;
#pragma unroll
                for (int nt = 0; nt < 5; ++nt) oacc[mi][nt][r] *= alpha[mi][r];
            }

        __threadfence_block();   // wave-private P region: lgkm drain only

        // ---- O += P.V ----
#pragma unroll
        for (int kc = 0; kc < 2; ++kc) {
            const int cbase = (kc * 32 + quad * 8) ^ (((ln >> 2) & 2) * 8);
            bf16x8 pf[3];
#pragma unroll
            for (int mi = 0; mi < 3; ++mi)
                pf[mi] = *(const bf16x8*)&PbW[(mi * 16 + ln) * 72 + cbase];
#pragma unroll
            for (int nt = 0; nt < 5; ++nt) {
                const int vrow = nt * 16 + ln;
                const int c8r  = ((kc * 4 + quad) + 3 * vrow) & 7;
                bf16x8 vf = *(const bf16x8*)&VtS[vrow * 64 + c8r * 8];
#pragma unroll
                for (int mi = 0; mi < 3; ++mi)
                    oacc[mi][nt] = mfma16(pf[mi], vf, oacc[mi][nt]);
            }
        }
    }

    // ---- epilogue (576 = 3*192: no masking) ----
#pragma unroll
    for (int mi = 0; mi < 3; ++mi)
#pragma unroll
        for (int r = 0; r < 4; ++r) {
            const int rr = qt * 192 + w * 48 + mi * 16 + quad * 4 + r;  // frame-local
            const float inv = 1.f / l_[mi][r];
            if (idx < 0) {
                const size_t orow = (size_t)f * SEQ + rr;
#pragma unroll
                for (int nt = 0; nt < 5; ++nt)
                    Oh[orow * DIM + h * HD + nt * 16 + ln] = f2bf(oacc[mi][nt][r] * inv);
            } else {
#pragma unroll
                for (int nt = 0; nt < 5; ++nt)
                    Pn[((size_t)idx * SEQ + rr) * DIM + h * HD + nt * 16 + ln] =
                        f2bf(oacc[mi][nt][r] * inv);
                if (ln == 0)
                    ml[((size_t)idx * 8 + h) * SEQ + rr] = make_float2(m_[mi][r], l_[mi][r]);
            }
        }
}

// ---------------------------------------------------------------------------
// Merge the two partials of each cross frame. grid=(576,8), block 320.
// ---------------------------------------------------------------------------
__global__ __launch_bounds__(320) void merge_kernel(
    const unsigned short* __restrict__ Pn, const float2* __restrict__ ml,
    unsigned short* __restrict__ Oh)
{
    const int row = blockIdx.x;   // 0..575
    const int fi  = blockIdx.y;   // 0..7
    const int t   = threadIdx.x;  // 0..319
    const int i0  = fi * 2, i1 = i0 + 1;
#pragma unroll
    for (int rep = 0; rep < 2; ++rep) {
        const int col = t + rep * 320;
        const int h = col / 80;
        const float2 a = ml[((size_t)i0 * 8 + h) * SEQ + row];
        const float2 b = ml[((size_t)i1 * 8 + h) * SEQ + row];
        const float M  = fmaxf(a.x, b.x);
        const float w0 = fexp2(a.x - M) * a.y;
        const float w1 = fexp2(b.x - M) * b.y;
        const float inv = 1.f / (w0 + w1);
        const float p0 = bf2f(Pn[((size_t)i0 * SEQ + row) * DIM + col]);
        const float p1 = bf2f(Pn[((size_t)i1 * SEQ + row) * DIM + col]);
        Oh[((size_t)(4 + fi) * SEQ + row) * DIM + col] = f2bf((w0 * p0 + w1 * p1) * inv);
    }
}

// ---------------------------------------------------------------------------
// Output projection: out = Oh * Wo^T + bo (single bf16), fp32 out.
// Tile 256x64, BK=32, global_load_lds staging. grid=(27,10).
// ---------------------------------------------------------------------------
__global__ __launch_bounds__(256) void oproj_mfma_kernel(
    const unsigned short* __restrict__ Oh,
    const unsigned short* __restrict__ Woh,
    const float* __restrict__ bo, float* __restrict__ out)
{
    __shared__ unsigned short smem[10240];
    unsigned short* As = smem;
    unsigned short* Bs = smem + 8192;

    const int m0 = blockIdx.x * 256;
    const int n0 = blockIdx.y * 64;

    const int t    = threadIdx.x;
    const int w    = t >> 6;
    const int lane = t & 63;
    const int quad = lane >> 4;
    const int ln   = lane & 15;

    f32x4 acc[4][4];
#pragma unroll
    for (int mi = 0; mi < 4; ++mi)
#pragma unroll
        for (int nt = 0; nt < 4; ++nt)
#pragma unroll
            for (int e = 0; e < 4; ++e) acc[mi][nt][e] = 0.f;

    const int lr = lane >> 2;
    const int lc = (lane & 3) * 8;

    for (int k0 = 0; k0 < DIM; k0 += 32) {
        __syncthreads();
        {
            const unsigned short* gp = Oh + (size_t)(m0 + w * 64 + lr) * DIM + k0 + lc;
#pragma unroll
            for (int i = 0; i < 4; ++i)
                dma16(gp + (size_t)i * 16 * DIM, &As[(w * 64 + i * 16) * 32]);
            const size_t gb = (size_t)(n0 + w * 16 + lr) * DIM + k0 + lc;
            dma16(Woh + gb, &Bs[w * 16 * 32]);
        }
        __syncthreads();

        bf16x8 af[4];
#pragma unroll
        for (int mi = 0; mi < 4; ++mi)
            af[mi] = *(const bf16x8*)&As[(w * 64 + mi * 16 + ln) * 32 + quad * 8];
#pragma unroll
        for (int nt = 0; nt < 4; ++nt) {
            bf16x8 bh = *(const bf16x8*)&Bs[(nt * 16 + ln) * 32 + quad * 8];
#pragma unroll
            for (int mi = 0; mi < 4; ++mi)
                acc[mi][nt] = mfma16(af[mi], bh, acc[mi][nt]);
        }
    }

#pragma unroll
    for (int mi = 0; mi < 4; ++mi)
#pragma unroll
        for (int r = 0; r < 4; ++r) {
            const size_t row = m0 + w * 64 + mi * 16 + quad * 4 + r;
#pragma unroll
            for (int nt = 0; nt < 4; ++nt) {
                const int col = n0 + nt * 16 + ln;
                out[row * DIM + col] = acc[mi][nt][r] + bo[col];
            }
        }
}

// ---------------------------------------------------------------------------
extern "C" void kernel_launch(void* const* d_in, const int* in_sizes, int n_in,
                              void* d_out, int out_size, void* d_ws, size_t ws_size,
                              hipStream_t stream)
{
    const float* x  = (const float*)d_in[0];
    const float* Wq = (const float*)d_in[1];
    const float* Wk = (const float*)d_in[2];
    const float* Wv = (const float*)d_in[3];
    const float* Wo = (const float*)d_in[4];
    const float* bo = (const float*)d_in[5];
    float* out = (float*)d_out;

    const size_t NX = (size_t)M_TOT * DIM;   // 4,423,680
    const size_t NW = (size_t)DIM * DIM;     // 409,600
    unsigned short* p = (unsigned short*)d_ws;
    unsigned short* Wqh = p;  p += NW;
    unsigned short* Wkh = p;  p += NW;
    unsigned short* Wvh = p;  p += NW;
    unsigned short* Woh = p;  p += NW;
    unsigned short* Xh  = p;  p += NX;
    unsigned short* Qhb = p;  p += NX;
    unsigned short* Kbb = p;  p += NX;
    unsigned short* Vtb = p;  p += NX;
    unsigned short* Ohb = Xh;                 // Xh dead after QKV GEMM

    // flash-decoding partials live in d_out (dead until oproj rewrites it)
    unsigned short* Pn = (unsigned short*)d_out;            // 16*576*640 bf16
    float2* ml = (float2*)((char*)d_out + (size_t)16 * SEQ * DIM * 2);

    dim3 g0((unsigned)((NX + 4095) / 4096), 5);
    split_kernel<<<g0, 256, 0, stream>>>(x, Wq, Wk, Wv, Wo,
        Xh, Wqh, Wkh, Wvh, Woh);

    dim3 g1(M_TOT / 256, DIM / 64, 3);
    qkv_mfma_kernel<<<g1, 256, 0, stream>>>(Xh, Wqh, Wkh, Wvh, Qhb, Kbb, Vtb);

    dim3 g2(3, HEADS, 20);
    attn_mfma_kernel<<<g2, 256, 0, stream>>>(Qhb, Kbb, Vtb, Ohb, Pn, ml);

    dim3 g3(SEQ, 8);
    merge_kernel<<<g3, 320, 0, stream>>>(Pn, ml, Ohb);

    dim3 g4(M_TOT / 256, DIM / 64);
    oproj_mfma_kernel<<<g4, 256, 0, stream>>>(Ohb, Woh, bo, out);
}

// Round 11
// 239.325 us; speedup vs baseline: 1.4845x; 1.1403x over previous
//
#include <hip/hip_runtime.h>
#include <hip/hip_bf16.h>

#define SEQ    576
#define DIM    640
#define HEADS  8
#define HD     80          // DIM / HEADS
#define NF     4
#define NB     12          // 3 * NF
#define M_TOT  (NB * SEQ)  // 6912
#define SCALE  0.11180339887498949f   // 1/sqrt(80)
#define LOG2E  1.4426950408889634f

typedef __attribute__((ext_vector_type(8))) short          bf16x8;
typedef __attribute__((ext_vector_type(4))) float          f32x4;
typedef __attribute__((ext_vector_type(8))) unsigned short u16x8;
typedef __attribute__((ext_vector_type(4))) unsigned short u16x4;

__device__ __forceinline__ unsigned short f2bf(float x) {
    unsigned u = __float_as_uint(x);
    u += 0x7fffu + ((u >> 16) & 1u);
    return (unsigned short)(u >> 16);
}
__device__ __forceinline__ float bf2f(unsigned short h) {
    return __uint_as_float((unsigned)h << 16);
}
__device__ __forceinline__ f32x4 mfma16(bf16x8 a, bf16x8 b, f32x4 c) {
    return __builtin_amdgcn_mfma_f32_16x16x32_bf16(a, b, c, 0, 0, 0);
}
__device__ __forceinline__ float fexp2(float x) {
    return __builtin_amdgcn_exp2f(x);
}
// async global->LDS DMA, 16B/lane, dest = lds base + lane*16
__device__ __forceinline__ void dma16(const void* g, void* s) {
    __builtin_amdgcn_global_load_lds(
        (const __attribute__((address_space(1))) void*)g,
        (__attribute__((address_space(3))) void*)s, 16, 0, 0);
}

// ---------------------------------------------------------------------------
// Convert fp32 -> bf16 (single, round-to-nearest). z: 0=X, 1=Wq(*SCALE*LOG2E),
// 2=Wk, 3=Wv, 4=Wo. grid=(1080,5), block 256, 16 elems/thread.
// ---------------------------------------------------------------------------
__global__ __launch_bounds__(256) void split_kernel(
    const float* __restrict__ X,  const float* __restrict__ Wq,
    const float* __restrict__ Wk, const float* __restrict__ Wv,
    const float* __restrict__ Wo,
    unsigned short* __restrict__ Xh,  unsigned short* __restrict__ Wqh,
    unsigned short* __restrict__ Wkh, unsigned short* __restrict__ Wvh,
    unsigned short* __restrict__ Woh)
{
    const int z = blockIdx.y;
    const float* src; unsigned short* dh; int n; float s = 1.0f;
    switch (z) {
        case 0:  src = X;  dh = Xh;  n = M_TOT * DIM; break;
        case 1:  src = Wq; dh = Wqh; n = DIM * DIM; s = SCALE * LOG2E; break;
        case 2:  src = Wk; dh = Wkh; n = DIM * DIM; break;
        case 3:  src = Wv; dh = Wvh; n = DIM * DIM; break;
        default: src = Wo; dh = Woh; n = DIM * DIM; break;
    }
    const int base = blockIdx.x * 4096 + threadIdx.x * 16;
    if (base >= n) return;
#pragma unroll
    for (int half = 0; half < 2; ++half) {
        const int b = base + half * 8;
        float4 a4 = *(const float4*)(src + b);
        float4 b4 = *(const float4*)(src + b + 4);
        float vv[8] = {a4.x, a4.y, a4.z, a4.w, b4.x, b4.y, b4.z, b4.w};
        union { unsigned short u[8]; u16x8 v; } ph;
#pragma unroll
        for (int j = 0; j < 8; ++j) ph.u[j] = f2bf(vv[j] * s);
        *(u16x8*)(dh + b) = ph.v;
    }
}

// ---------------------------------------------------------------------------
// QKV GEMM (single bf16). Tile 256(M) x 64(N), BK=32, block 256.
// Staging via global_load_lds (16B/lane), unpadded [r][32] LDS.
// grid=(27,10,3); z epilogue: 0 -> Qh bf16, 1 -> Kb bf16, 2 -> Vt transpose.
// ---------------------------------------------------------------------------
__global__ __launch_bounds__(256) void qkv_mfma_kernel(
    const unsigned short* __restrict__ Xh,
    const unsigned short* __restrict__ Wqh, const unsigned short* __restrict__ Wkh,
    const unsigned short* __restrict__ Wvh,
    unsigned short* __restrict__ Qh,
    unsigned short* __restrict__ Kb, unsigned short* __restrict__ VtG)
{
    __shared__ unsigned short smem[10240];      // 20 KB
    unsigned short* As = smem;                  // 256*32
    unsigned short* Bs = smem + 8192;           // 64*32

    const int z = blockIdx.z;
    const unsigned short* WH = (z == 0) ? Wqh : ((z == 1) ? Wkh : Wvh);
    const int m0 = blockIdx.x * 256;
    const int n0 = blockIdx.y * 64;

    const int t    = threadIdx.x;
    const int w    = t >> 6;
    const int lane = t & 63;
    const int quad = lane >> 4;
    const int ln   = lane & 15;

    f32x4 acc[4][4];
#pragma unroll
    for (int mi = 0; mi < 4; ++mi)
#pragma unroll
        for (int nt = 0; nt < 4; ++nt)
#pragma unroll
            for (int e = 0; e < 4; ++e) acc[mi][nt][e] = 0.f;

    const int lr = lane >> 2;          // 0..15 (row within 16-row DMA chunk)
    const int lc = (lane & 3) * 8;     // 0,8,16,24 (shorts)

    for (int k0 = 0; k0 < DIM; k0 += 32) {
        __syncthreads();
        {   // A: wave w stages its own 64 rows (4 x 1KB DMA)
            const unsigned short* gp = Xh + (size_t)(m0 + w * 64 + lr) * DIM + k0 + lc;
#pragma unroll
            for (int i = 0; i < 4; ++i)
                dma16(gp + (size_t)i * 16 * DIM, &As[(w * 64 + i * 16) * 32]);
            // B: wave w stages rows [w*16, w*16+16)
            const size_t gb = (size_t)(n0 + w * 16 + lr) * DIM + k0 + lc;
            dma16(WH + gb, &Bs[w * 16 * 32]);
        }
        __syncthreads();

        bf16x8 af[4];
#pragma unroll
        for (int mi = 0; mi < 4; ++mi)
            af[mi] = *(const bf16x8*)&As[(w * 64 + mi * 16 + ln) * 32 + quad * 8];
#pragma unroll
        for (int nt = 0; nt < 4; ++nt) {
            bf16x8 bh = *(const bf16x8*)&Bs[(nt * 16 + ln) * 32 + quad * 8];
#pragma unroll
            for (int mi = 0; mi < 4; ++mi)
                acc[mi][nt] = mfma16(af[mi], bh, acc[mi][nt]);
        }
    }

    if (z == 0) {
#pragma unroll
        for (int mi = 0; mi < 4; ++mi)
#pragma unroll
            for (int r = 0; r < 4; ++r) {
                const size_t row = m0 + w * 64 + mi * 16 + quad * 4 + r;
#pragma unroll
                for (int nt = 0; nt < 4; ++nt)
                    Qh[row * DIM + n0 + nt * 16 + ln] = f2bf(acc[mi][nt][r]);
            }
    } else if (z == 1) {
#pragma unroll
        for (int mi = 0; mi < 4; ++mi)
#pragma unroll
            for (int r = 0; r < 4; ++r) {
                const size_t row = m0 + w * 64 + mi * 16 + quad * 4 + r;
#pragma unroll
                for (int nt = 0; nt < 4; ++nt)
                    Kb[row * DIM + n0 + nt * 16 + ln] = f2bf(acc[mi][nt][r]);
            }
    } else {
        // transpose 256x64 -> Vt[64 n][256 m] in two 128-col halves via LDS
        unsigned short* Vts = smem;   // 64 x 136 = 8704 shorts
#pragma unroll 1
        for (int half = 0; half < 2; ++half) {
            __syncthreads();
            if ((w >> 1) == half) {
                const int wl = w & 1;
#pragma unroll
                for (int mi = 0; mi < 4; ++mi)
#pragma unroll
                    for (int nt = 0; nt < 4; ++nt)
#pragma unroll
                        for (int r = 0; r < 4; ++r)
                            Vts[(nt * 16 + ln) * 136 + wl * 64 + mi * 16 + quad * 4 + r] =
                                f2bf(acc[mi][nt][r]);
            }
            __syncthreads();
            const int nn = t & 63;
            const int c0 = (t >> 6) * 32;
#pragma unroll
            for (int i = 0; i < 4; ++i)
                *(u16x8*)(VtG + (size_t)(n0 + nn) * M_TOT + m0 + half * 128 + c0 + i * 8) =
                    *(const u16x8*)&Vts[nn * 136 + c0 + i * 8];
        }
    }
}

// ---------------------------------------------------------------------------
// Flash attention v7 (S-transposed). grid=(3,8,20), block 256 (4 waves x 48
// q-rows). S^T = K.Q^T via swapped MFMA operands: lane holds one q-row's
// logits -> softmax state is per-lane scalar (2 shuffles/mi over quads), and
// P stores become 12 ds_write_b64 into row-major Pb[q][key] (bank-uniform,
// = b64 floor) while PV still reads contiguous b128 A-frags. This cut the
// LDS-pipe census 172 -> ~64 ops/wave/iter (round-10 bottleneck).
// NOTE: never leave MFMA-read LDS uninitialized — 0*NaN = NaN (round-7 bug).
// NOTE: 128-thread blocks double FETCH + VGPR (round-9 regression) — keep 256.
// z<16: cross chunk -> partials (Pn,ml); z>=16: self frame -> Oh.
// ---------------------------------------------------------------------------
__global__ __launch_bounds__(256, 2) void attn_mfma_kernel(
    const unsigned short* __restrict__ Qh,
    const unsigned short* __restrict__ Kb, const unsigned short* __restrict__ Vt,
    unsigned short* __restrict__ Oh,
    unsigned short* __restrict__ Pn, float2* __restrict__ ml)
{
    const int qt = blockIdx.x;   // 0..2
    const int h  = blockIdx.y;   // 0..7
    const int z  = blockIdx.z;   // 0..19

    int f, kbase, nkt, idx = -1;
    if (z < 16) {
        idx = z;
        const int fi = z >> 1;
        f = 4 + fi;
        kbase = ((fi < 4 ? 4 : 8) + (z & 1) * 2) * SEQ;
        nkt = 18;
    } else {
        f = z - 16;
        kbase = f * SEQ;
        nkt = 9;
    }

    const int t    = threadIdx.x;
    const int w    = t >> 6;
    const int lane = t & 63;
    const int quad = lane >> 4;
    const int ln   = lane & 15;

    __shared__ unsigned short KhS[64 * 96];    // DMA-staged, fully written/iter
    __shared__ unsigned short VtS[80 * 64];    // exact-fit, swizzled cols
    __shared__ unsigned short Pb[4 * 48 * 72]; // per-wave P[q][key], b64-stored

    // ---- Q fragments (B-operand of S^T; same lane mapping as A was) ----
    bf16x8 qf[3][3];
#pragma unroll
    for (int mi = 0; mi < 3; ++mi) {
        const int qrow = f * SEQ + qt * 192 + w * 48 + mi * 16 + ln;
        const unsigned short* qp = Qh + (size_t)qrow * DIM + h * HD;
#pragma unroll
        for (int kc = 0; kc < 3; ++kc) {
            const int dbase = kc * 32 + quad * 8;
            if (dbase < HD) {
                qf[mi][kc] = *(const bf16x8*)(qp + dbase);
            } else {
                union { unsigned short u[8]; bf16x8 v; } zz;
#pragma unroll
                for (int j = 0; j < 8; ++j) zz.u[j] = 0;
                qf[mi][kc] = zz.v;
            }
        }
    }

    // per-lane softmax state for q = mi*16 + ln (replicated across quads)
    float m_[3], l_[3];
#pragma unroll
    for (int mi = 0; mi < 3; ++mi) { m_[mi] = -INFINITY; l_[mi] = 0.f; }

    f32x4 oacc[3][5];
#pragma unroll
    for (int mi = 0; mi < 3; ++mi)
#pragma unroll
        for (int nt = 0; nt < 5; ++nt)
#pragma unroll
            for (int e = 0; e < 4; ++e) oacc[mi][nt][e] = 0.f;

    unsigned short* PbW = &Pb[w * 48 * 72];

    for (int kt = 0; kt < nkt; ++kt) {
        __syncthreads();
        {   // ---- K stage via DMA: 64 rows x 96 shorts = 768 units, 3 rounds ----
            const unsigned short* kg = Kb + (size_t)(kbase + kt * 64) * DIM + h * HD;
#pragma unroll
            for (int rnd = 0; rnd < 3; ++rnd) {
                const int unit = rnd * 256 + t;
                const int kr = unit / 12, kc = unit % 12;
                dma16(kg + (size_t)kr * DIM + kc * 8,
                      &KhS[(rnd * 256 + w * 64) * 8]);
            }
        }
        {   // ---- V stage: 80 d-rows x 64 keys, swizzled col-groups ----
#pragma unroll
            for (int u = t; u < 640; u += 256) {
                const int d = u >> 3, c8 = u & 7;
                const int c8s = (c8 + 3 * d) & 7;
                *(u16x8*)&VtS[d * 64 + c8s * 8] =
                    *(const u16x8*)(Vt + (size_t)(h * HD + d) * M_TOT +
                                    kbase + kt * 64 + c8 * 8);
            }
        }
        __syncthreads();

        // ---- S^T = K.Q^T: lane holds S[q=mi*16+ln][key=nt*16+quad*4+r] ----
        f32x4 sacc[3][4];
#pragma unroll
        for (int mi = 0; mi < 3; ++mi)
#pragma unroll
            for (int nt = 0; nt < 4; ++nt)
#pragma unroll
                for (int e = 0; e < 4; ++e) sacc[mi][nt][e] = 0.f;
#pragma unroll
        for (int nt = 0; nt < 4; ++nt)
#pragma unroll
            for (int kc = 0; kc < 3; ++kc) {
                bf16x8 kf = *(const bf16x8*)&KhS[(nt * 16 + ln) * 96 + kc * 32 + quad * 8];
#pragma unroll
                for (int mi = 0; mi < 3; ++mi)
                    sacc[mi][nt] = mfma16(kf, qf[mi][kc], sacc[mi][nt]);  // swapped!
            }

        // ---- softmax: per-lane row state, reduce over quads only ----
        float aq[3];
#pragma unroll
        for (int mi = 0; mi < 3; ++mi) {
            float mx = sacc[mi][0][0];
#pragma unroll
            for (int nt = 0; nt < 4; ++nt)
#pragma unroll
                for (int r = 0; r < 4; ++r) mx = fmaxf(mx, sacc[mi][nt][r]);
            mx = fmaxf(mx, __shfl_xor(mx, 16));
            mx = fmaxf(mx, __shfl_xor(mx, 32));
            const float mnew = fmaxf(m_[mi], mx);
            aq[mi] = fexp2(m_[mi] - mnew);
            m_[mi] = mnew;
            float s = 0.f;
#pragma unroll
            for (int nt = 0; nt < 4; ++nt) {
                union { unsigned short u[4]; u16x4 v; } pk;
#pragma unroll
                for (int r = 0; r < 4; ++r) {
                    const float p = fexp2(sacc[mi][nt][r] - m_[mi]);
                    s += p;
                    pk.u[r] = (unsigned short)(__float_as_uint(p) >> 16);  // trunc bf16
                }
                *(u16x4*)&PbW[(mi * 16 + ln) * 72 + nt * 16 + quad * 4] = pk.v;
            }
            s += __shfl_xor(s, 16);
            s += __shfl_xor(s, 32);
            l_[mi] = l_[mi] * aq[mi] + s;
        }

        // ---- rescale oacc (rows q=quad*4+r; alpha lives at lane q) ----
#pragma unroll
        for (int mi = 0; mi < 3; ++mi)
#pragma unroll
            for (int r = 0; r < 4; ++r) {
                const float ar = __shfl(aq[mi], quad * 4 + r, 64);
#pragma unroll
                for (int nt = 0; nt < 5; ++nt) oacc[mi][nt][r] *= ar;
            }

        __threadfence_block();   // wave-private P region: lgkm drain only

        // ---- O += P.V (P A-frag b128 from row-major Pb[q][key]) ----
#pragma unroll
        for (int kc = 0; kc < 2; ++kc) {
            bf16x8 pf[3];
#pragma unroll
            for (int mi = 0; mi < 3; ++mi)
                pf[mi] = *(const bf16x8*)&PbW[(mi * 16 + ln) * 72 + kc * 32 + quad * 8];
#pragma unroll
            for (int nt = 0; nt < 5; ++nt) {
                const int vrow = nt * 16 + ln;
                const int c8r  = ((kc * 4 + quad) + 3 * vrow) & 7;
                bf16x8 vf = *(const bf16x8*)&VtS[vrow * 64 + c8r * 8];
#pragma unroll
                for (int mi = 0; mi < 3; ++mi)
                    oacc[mi][nt] = mfma16(pf[mi], vf, oacc[mi][nt]);
            }
        }
    }

    // ---- epilogue (l lives at lane q; fetch per-row via shfl) ----
#pragma unroll
    for (int mi = 0; mi < 3; ++mi)
#pragma unroll
        for (int r = 0; r < 4; ++r) {
            const float lr_ = __shfl(l_[mi], quad * 4 + r, 64);
            const float inv = 1.f / lr_;
            const int rr = qt * 192 + w * 48 + mi * 16 + quad * 4 + r;  // frame-local
            if (idx < 0) {
                const size_t orow = (size_t)f * SEQ + rr;
#pragma unroll
                for (int nt = 0; nt < 5; ++nt)
                    Oh[orow * DIM + h * HD + nt * 16 + ln] = f2bf(oacc[mi][nt][r] * inv);
            } else {
#pragma unroll
                for (int nt = 0; nt < 5; ++nt)
                    Pn[((size_t)idx * SEQ + rr) * DIM + h * HD + nt * 16 + ln] =
                        f2bf(oacc[mi][nt][r] * inv);
            }
        }
    if (idx >= 0 && lane < 16) {
#pragma unroll
        for (int mi = 0; mi < 3; ++mi) {
            const int rr = qt * 192 + w * 48 + mi * 16 + lane;
            ml[((size_t)idx * 8 + h) * SEQ + rr] = make_float2(m_[mi], l_[mi]);
        }
    }
}

// ---------------------------------------------------------------------------
// Merge the two partials of each cross frame. grid=(576,8), block 320.
// ---------------------------------------------------------------------------
__global__ __launch_bounds__(320) void merge_kernel(
    const unsigned short* __restrict__ Pn, const float2* __restrict__ ml,
    unsigned short* __restrict__ Oh)
{
    const int row = blockIdx.x;   // 0..575
    const int fi  = blockIdx.y;   // 0..7
    const int t   = threadIdx.x;  // 0..319
    const int i0  = fi * 2, i1 = i0 + 1;
#pragma unroll
    for (int rep = 0; rep < 2; ++rep) {
        const int col = t + rep * 320;
        const int h = col / 80;
        const float2 a = ml[((size_t)i0 * 8 + h) * SEQ + row];
        const float2 b = ml[((size_t)i1 * 8 + h) * SEQ + row];
        const float M  = fmaxf(a.x, b.x);
        const float w0 = fexp2(a.x - M) * a.y;
        const float w1 = fexp2(b.x - M) * b.y;
        const float inv = 1.f / (w0 + w1);
        const float p0 = bf2f(Pn[((size_t)i0 * SEQ + row) * DIM + col]);
        const float p1 = bf2f(Pn[((size_t)i1 * SEQ + row) * DIM + col]);
        Oh[((size_t)(4 + fi) * SEQ + row) * DIM + col] = f2bf((w0 * p0 + w1 * p1) * inv);
    }
}

// ---------------------------------------------------------------------------
// Output projection: out = Oh * Wo^T + bo (single bf16), fp32 out.
// Tile 256x64, BK=32, global_load_lds staging. grid=(27,10).
// ---------------------------------------------------------------------------
__global__ __launch_bounds__(256) void oproj_mfma_kernel(
    const unsigned short* __restrict__ Oh,
    const unsigned short* __restrict__ Woh,
    const float* __restrict__ bo, float* __restrict__ out)
{
    __shared__ unsigned short smem[10240];
    unsigned short* As = smem;
    unsigned short* Bs = smem + 8192;

    const int m0 = blockIdx.x * 256;
    const int n0 = blockIdx.y * 64;

    const int t    = threadIdx.x;
    const int w    = t >> 6;
    const int lane = t & 63;
    const int quad = lane >> 4;
    const int ln   = lane & 15;

    f32x4 acc[4][4];
#pragma unroll
    for (int mi = 0; mi < 4; ++mi)
#pragma unroll
        for (int nt = 0; nt < 4; ++nt)
#pragma unroll
            for (int e = 0; e < 4; ++e) acc[mi][nt][e] = 0.f;

    const int lr = lane >> 2;
    const int lc = (lane & 3) * 8;

    for (int k0 = 0; k0 < DIM; k0 += 32) {
        __syncthreads();
        {
            const unsigned short* gp = Oh + (size_t)(m0 + w * 64 + lr) * DIM + k0 + lc;
#pragma unroll
            for (int i = 0; i < 4; ++i)
                dma16(gp + (size_t)i * 16 * DIM, &As[(w * 64 + i * 16) * 32]);
            const size_t gb = (size_t)(n0 + w * 16 + lr) * DIM + k0 + lc;
            dma16(Woh + gb, &Bs[w * 16 * 32]);
        }
        __syncthreads();

        bf16x8 af[4];
#pragma unroll
        for (int mi = 0; mi < 4; ++mi)
            af[mi] = *(const bf16x8*)&As[(w * 64 + mi * 16 + ln) * 32 + quad * 8];
#pragma unroll
        for (int nt = 0; nt < 4; ++nt) {
            bf16x8 bh = *(const bf16x8*)&Bs[(nt * 16 + ln) * 32 + quad * 8];
#pragma unroll
            for (int mi = 0; mi < 4; ++mi)
                acc[mi][nt] = mfma16(af[mi], bh, acc[mi][nt]);
        }
    }

#pragma unroll
    for (int mi = 0; mi < 4; ++mi)
#pragma unroll
        for (int r = 0; r < 4; ++r) {
            const size_t row = m0 + w * 64 + mi * 16 + quad * 4 + r;
#pragma unroll
            for (int nt = 0; nt < 4; ++nt) {
                const int col = n0 + nt * 16 + ln;
                out[row * DIM + col] = acc[mi][nt][r] + bo[col];
            }
        }
}

// ---------------------------------------------------------------------------
extern "C" void kernel_launch(void* const* d_in, const int* in_sizes, int n_in,
                              void* d_out, int out_size, void* d_ws, size_t ws_size,
                              hipStream_t stream)
{
    const float* x  = (const float*)d_in[0];
    const float* Wq = (const float*)d_in[1];
    const float* Wk = (const float*)d_in[2];
    const float* Wv = (const float*)d_in[3];
    const float* Wo = (const float*)d_in[4];
    const float* bo = (const float*)d_in[5];
    float* out = (float*)d_out;

    const size_t NX = (size_t)M_TOT * DIM;   // 4,423,680
    const size_t NW = (size_t)DIM * DIM;     // 409,600
    unsigned short* p = (unsigned short*)d_ws;
    unsigned short* Wqh = p;  p += NW;
    unsigned short* Wkh = p;  p += NW;
    unsigned short* Wvh = p;  p += NW;
    unsigned short* Woh = p;  p += NW;
    unsigned short* Xh  = p;  p += NX;
    unsigned short* Qhb = p;  p += NX;
    unsigned short* Kbb = p;  p += NX;
    unsigned short* Vtb = p;  p += NX;
    unsigned short* Ohb = Xh;                 // Xh dead after QKV GEMM

    // flash-decoding partials live in d_out (dead until oproj rewrites it)
    unsigned short* Pn = (unsigned short*)d_out;            // 16*576*640 bf16
    float2* ml = (float2*)((char*)d_out + (size_t)16 * SEQ * DIM * 2);

    dim3 g0((unsigned)((NX + 4095) / 4096), 5);
    split_kernel<<<g0, 256, 0, stream>>>(x, Wq, Wk, Wv, Wo,
        Xh, Wqh, Wkh, Wvh, Woh);

    dim3 g1(M_TOT / 256, DIM / 64, 3);
    qkv_mfma_kernel<<<g1, 256, 0, stream>>>(Xh, Wqh, Wkh, Wvh, Qhb, Kbb, Vtb);

    dim3 g2(3, HEADS, 20);
    attn_mfma_kernel<<<g2, 256, 0, stream>>>(Qhb, Kbb, Vtb, Ohb, Pn, ml);

    dim3 g3(SEQ, 8);
    merge_kernel<<<g3, 320, 0, stream>>>(Pn, ml, Ohb);

    dim3 g4(M_TOT / 256, DIM / 64);
    oproj_mfma_kernel<<<g4, 256, 0, stream>>>(Ohb, Woh, bo, out);
}